// Round 1
// baseline (134.170 us; speedup 1.0000x reference)
//
#include <hip/hip_runtime.h>

#define EPS 1e-7f
#define T_DIM 2048
#define TP1   2049
#define H_DIM 8
#define B_DIM 8
#define D_DIM 64
#define SP    2080   // padded xT row length (bf16 elements), 16B-aligned rows
#define KLEN  2272   // khx per-head length (elements)
#define KOFF  128    // zero-pad offset so negative distances read 0

typedef short v8s __attribute__((ext_vector_type(8)));
typedef float v4f __attribute__((ext_vector_type(4)));

static __device__ __forceinline__ unsigned short f2bf(float f) {
  union { float f; unsigned u; } v; v.f = f;
  unsigned r = v.u + 0x7fffu + ((v.u >> 16) & 1u);  // RTNE
  return (unsigned short)(r >> 16);
}

// khx[h][i] = k_h[i - KOFF];  k_h[d] = exp(W[d,h]) for 0<=d<2048, 1.0 at d==2048, else 0
__global__ __launch_bounds__(256) void build_khx(const float* __restrict__ W,
                                                 unsigned short* __restrict__ khx) {
  int idx = blockIdx.x * 256 + threadIdx.x;
  if (idx >= H_DIM * KLEN) return;
  int h = idx / KLEN, i = idx - h * KLEN;
  int d = i - KOFF;
  float v = 0.0f;
  if (d >= 0 && d < T_DIM) v = __expf(W[d * H_DIM + h]);
  else if (d == T_DIM) v = 1.0f;
  khx[idx] = f2bf(v);
}

// xT[b][dd][s] (bf16, row stride SP), s in [0,2080): x transposed per batch, zero-padded
__global__ __launch_bounds__(256) void transpose_x(const float* __restrict__ x,
                                                   unsigned short* __restrict__ xT) {
  int b = blockIdx.x / 33, st = blockIdx.x % 33;
  int tid = threadIdx.x;
  if (st == 32) {  // zero pad s in [2048, 2080)
    #pragma unroll
    for (int i = 0; i < 8; ++i) {
      int idx = tid * 8 + i;
      int dd = idx >> 5, sl = idx & 31;
      xT[((size_t)b * D_DIM + dd) * SP + T_DIM + sl] = 0;
    }
    return;
  }
  __shared__ float tile[64][65];
  int s0 = st * 64;
  int c = tid & 63, r4 = tid >> 6;
  #pragma unroll
  for (int i = 0; i < 16; ++i) {
    int sl = r4 * 16 + i;
    tile[sl][c] = x[((size_t)b * T_DIM + (s0 + sl)) * D_DIM + c];
  }
  __syncthreads();
  #pragma unroll
  for (int i = 0; i < 16; ++i) {
    int dd = r4 * 16 + i;
    xT[((size_t)b * D_DIM + dd) * SP + s0 + c] = f2bf(tile[c][dd]);
  }
}

// One wave per 64(t) x 64(dd) tile for one (h, b). Causal K loop over s-tiles of 32.
// E[t][s] = k_h[t-s] built per-lane from khx (L1-hot); X fragments read directly
// from global xT (aligned 16B). No LDS, no syncthreads.
__global__ __launch_bounds__(64) void toeplitz_mm(const unsigned short* __restrict__ khx,
                                                  const unsigned short* __restrict__ xT,
                                                  float* __restrict__ out) {
  const int lane = threadIdx.x;
  const int lm   = lane & 15;
  const int quad = lane >> 4;

  const int bi  = blockIdx.x;
  const int tt  = 32 - (bi >> 6);          // longest tiles first
  const int rem = bi & 63;
  const int h = rem >> 3, b = rem & 7;
  const int t0 = tt * 64;

  const unsigned short* kh = khx + h * KLEN + KOFF;
  const unsigned short* xb = xT + (size_t)b * D_DIM * SP;

  v4f acc[4][4] = {};  // [mt][nt], rows t0+16*mt+..., cols 16*nt+lm

  const int s_end = min(t0 + 32, T_DIM);   // last s0 (inclusive)

  // A fragment (16x16x32): A[m=lane&15][k=quad*8+j] = k_h[(t0+16*mt+lm) - (s0+8*quad+j)]
  auto loadA = [&](int mt, int s0) -> v8s {
    v8s f;
    int base = t0 + 16 * mt + lm - s0 - 8 * quad;
    #pragma unroll
    for (int j = 0; j < 8; ++j) f[j] = (short)kh[base - j];
    return f;
  };
  // B fragment: B[k=quad*8+j][n=lane&15] = xT[b][16*nt+lm][s0+8*quad+j]
  auto loadB = [&](int nt, int s0) -> v8s {
    const unsigned short* p = xb + (size_t)(16 * nt + lm) * SP + s0 + 8 * quad;
    return *(const v8s*)p;
  };

  v8s fa[4], fb[4];
  #pragma unroll
  for (int mt = 0; mt < 4; ++mt) fa[mt] = loadA(mt, 0);
  #pragma unroll
  for (int nt = 0; nt < 4; ++nt) fb[nt] = loadB(nt, 0);

  for (int s0 = 0;; s0 += 32) {
    const bool more = s0 < s_end;
    v8s na0, na1, nb[4];
    if (more) {  // prefetch next K-step (wave-uniform branch)
      #pragma unroll
      for (int nt = 0; nt < 4; ++nt) nb[nt] = loadB(nt, s0 + 32);
      na0 = loadA(0, s0 + 32);
      na1 = loadA(1, s0 + 32);
    }
    #pragma unroll
    for (int mt = 0; mt < 4; ++mt)
      #pragma unroll
      for (int nt = 0; nt < 4; ++nt)
        acc[mt][nt] = __builtin_amdgcn_mfma_f32_16x16x32_bf16(fa[mt], fb[nt], acc[mt][nt], 0, 0, 0);
    if (!more) break;
    // shift by 32 in distance: frag(mt) at s0+32 == frag(mt-2) at s0
    fa[3] = fa[1]; fa[2] = fa[0]; fa[1] = na1; fa[0] = na0;
    #pragma unroll
    for (int nt = 0; nt < 4; ++nt) fb[nt] = nb[nt];
  }

  // Epilogue: double l2-norm over dd (Z cancels up to eps terms ~3e-7).
  // C/D layout: col = lane&15 (dd offset), row = quad*4 + reg.
  #pragma unroll
  for (int mt = 0; mt < 4; ++mt) {
    #pragma unroll
    for (int r = 0; r < 4; ++r) {
      float ss = 0.0f;
      #pragma unroll
      for (int nt = 0; nt < 4; ++nt) { float a = acc[mt][nt][r]; ss += a * a; }
      ss += __shfl_xor(ss, 1);
      ss += __shfl_xor(ss, 2);
      ss += __shfl_xor(ss, 4);
      ss += __shfl_xor(ss, 8);
      int t = t0 + 16 * mt + 4 * quad + r;
      if (t <= T_DIM) {
        float n1 = sqrtf(ss);
        float u  = n1 / (n1 + EPS);
        float inv = 1.0f / ((n1 + EPS) * (u + EPS));
        float* op = out + (((size_t)(h * B_DIM + b) * TP1 + t) << 6) + lm;
        #pragma unroll
        for (int nt = 0; nt < 4; ++nt) op[16 * nt] = acc[mt][nt][r] * inv;
      }
    }
  }
}

// Head H: single l2norm of xp
__global__ __launch_bounds__(64) void xhat_out(const float* __restrict__ x,
                                               float* __restrict__ out) {
  int row = blockIdx.x;  // 8*2049
  int b = row / TP1, t = row - b * TP1;
  int dd = threadIdx.x;
  float v = (t < T_DIM) ? x[((size_t)b * T_DIM + t) * D_DIM + dd] : 0.0f;
  float ss = v * v;
  ss += __shfl_xor(ss, 1);
  ss += __shfl_xor(ss, 2);
  ss += __shfl_xor(ss, 4);
  ss += __shfl_xor(ss, 8);
  ss += __shfl_xor(ss, 16);
  ss += __shfl_xor(ss, 32);
  float inv = 1.0f / (sqrtf(ss) + EPS);
  out[(((size_t)(H_DIM * B_DIM + b) * TP1 + t) << 6) + dd] = v * inv;
}

extern "C" void kernel_launch(void* const* d_in, const int* in_sizes, int n_in,
                              void* d_out, int out_size, void* d_ws, size_t ws_size,
                              hipStream_t stream) {
  const float* x = (const float*)d_in[0];   // [8, 2048, 64] fp32
  const float* W = (const float*)d_in[1];   // [2048, 8] fp32
  float* out = (float*)d_out;               // [9, 8, 2049, 64] fp32

  unsigned short* khx = (unsigned short*)d_ws;                      // 8*2272*2 = 36352 B
  unsigned short* xT  = (unsigned short*)((char*)d_ws + 36864);     // 8*64*2080*2 = 2129920 B

  hipLaunchKernelGGL(build_khx, dim3((H_DIM * KLEN + 255) / 256), dim3(256), 0, stream, W, khx);
  hipLaunchKernelGGL(transpose_x, dim3(B_DIM * 33), dim3(256), 0, stream, x, xT);
  hipLaunchKernelGGL(toeplitz_mm, dim3(64 * 33), dim3(64), 0, stream, khx, xT, out);
  hipLaunchKernelGGL(xhat_out, dim3(B_DIM * TP1), dim3(64), 0, stream, x, out);
}

// Round 2
// 126.163 us; speedup vs baseline: 1.0635x; 1.0635x over previous
//
#include <hip/hip_runtime.h>

#define EPS 1e-7f
#define T_DIM 2048
#define TP1   2049
#define H_DIM 8
#define B_DIM 8
#define D_DIM 64
#define SP    2080   // padded xT row length (bf16 elements), 16B-aligned rows
#define NFRAG 134    // A-fragment table entries per head: b0 = fb*16 - 32, fb in [0,134)
#define FB_OFF 32

typedef short v8s __attribute__((ext_vector_type(8)));
typedef float v4f __attribute__((ext_vector_type(4)));

static __device__ __forceinline__ unsigned short f2bf(float f) {
  union { float f; unsigned u; } v; v.f = f;
  unsigned r = v.u + 0x7fffu + ((v.u >> 16) & 1u);  // RTNE
  return (unsigned short)(r >> 16);
}

// Pre-built MFMA A-fragments. Fragment (h, b0): A[m=lm][k=quad*8+j] = k_h[b0 + lm - 8*quad - j],
// k_h[d] = exp(W[d,h]) for 0<=d<2048, 1.0 at d==2048, 0 otherwise.
// Layout: fragA[((h*NFRAG + fb)*64 + lane)*8], 16B per lane -> single aligned dwordx4 load.
__global__ __launch_bounds__(64) void build_fragA(const float* __restrict__ W,
                                                  unsigned short* __restrict__ fragA) {
  const int blk = blockIdx.x;            // h*NFRAG + fb
  const int h = blk / NFRAG, fb = blk - h * NFRAG;
  const int b0 = fb * 16 - FB_OFF;
  const int lane = threadIdx.x;
  const int lm = lane & 15, quad = lane >> 4;
  v8s frag;
  #pragma unroll
  for (int j = 0; j < 8; ++j) {
    int d = b0 + lm - 8 * quad - j;
    float v = 0.0f;
    if (d >= 0 && d < T_DIM) v = __expf(W[d * H_DIM + h]);
    else if (d == T_DIM) v = 1.0f;
    frag[j] = (short)f2bf(v);
  }
  *(v8s*)(fragA + ((size_t)(blk * 64 + lane)) * 8) = frag;
}

// xT[b][dd][s] (bf16, row stride SP), s in [0,2080): x transposed per batch, zero-padded
__global__ __launch_bounds__(256) void transpose_x(const float* __restrict__ x,
                                                   unsigned short* __restrict__ xT) {
  int b = blockIdx.x / 33, st = blockIdx.x % 33;
  int tid = threadIdx.x;
  if (st == 32) {  // zero pad s in [2048, 2080)
    #pragma unroll
    for (int i = 0; i < 8; ++i) {
      int idx = tid * 8 + i;
      int dd = idx >> 5, sl = idx & 31;
      xT[((size_t)b * D_DIM + dd) * SP + T_DIM + sl] = 0;
    }
    return;
  }
  __shared__ float tile[64][65];
  int s0 = st * 64;
  int c = tid & 63, r4 = tid >> 6;
  #pragma unroll
  for (int i = 0; i < 16; ++i) {
    int sl = r4 * 16 + i;
    tile[sl][c] = x[((size_t)b * T_DIM + (s0 + sl)) * D_DIM + c];
  }
  __syncthreads();
  #pragma unroll
  for (int i = 0; i < 16; ++i) {
    int dd = r4 * 16 + i;
    xT[((size_t)b * D_DIM + dd) * SP + s0 + c] = f2bf(tile[c][dd]);
  }
}

// One wave per 64(t) x 64(dd) tile for one (h, b). Causal K loop over s-tiles of 32.
// A fragments: single dwordx4 from the precomputed table (L2-hot).
// B fragments: single dwordx4 from xT. No LDS, no syncthreads.
__global__ __launch_bounds__(64) void toeplitz_mm(const unsigned short* __restrict__ fragA,
                                                  const unsigned short* __restrict__ xT,
                                                  float* __restrict__ out) {
  const int lane = threadIdx.x;
  const int lm   = lane & 15;
  const int quad = lane >> 4;

  const int bi  = blockIdx.x;
  const int tt  = 32 - (bi >> 6);          // longest tiles first
  const int rem = bi & 63;
  const int h = rem >> 3, b = rem & 7;
  const int t0 = tt * 64;

  const unsigned short* fA = fragA + ((size_t)h * NFRAG * 64 + lane) * 8;
  const unsigned short* xb = xT + (size_t)b * D_DIM * SP;

  v4f acc[4][4] = {};  // [mt][nt], rows t0+16*mt+4*quad+r, cols 16*nt+lm

  const int s_end = min(t0 + 32, T_DIM);   // last s0 (exclusive bound for prefetch)

  // A fragment for (mt, s0): table entry fb = (t0 + 16*mt - s0 + FB_OFF) >> 4
  auto loadA = [&](int mt, int s0) -> v8s {
    int fb = (t0 + 16 * mt - s0 + FB_OFF) >> 4;
    return *(const v8s*)(fA + (size_t)fb * 64 * 8);
  };
  // B fragment: B[k=quad*8+j][n=lm] = xT[b][16*nt+lm][s0+8*quad+j]
  auto loadB = [&](int nt, int s0) -> v8s {
    const unsigned short* p = xb + (size_t)(16 * nt + lm) * SP + s0 + 8 * quad;
    return *(const v8s*)p;
  };

  v8s fa[4], fbr[4];
  #pragma unroll
  for (int mt = 0; mt < 4; ++mt) fa[mt] = loadA(mt, 0);
  #pragma unroll
  for (int nt = 0; nt < 4; ++nt) fbr[nt] = loadB(nt, 0);

  for (int s0 = 0;; s0 += 32) {
    const bool more = s0 < s_end;
    v8s na0, na1, nb[4];
    if (more) {  // prefetch next K-step (wave-uniform branch)
      #pragma unroll
      for (int nt = 0; nt < 4; ++nt) nb[nt] = loadB(nt, s0 + 32);
      na0 = loadA(0, s0 + 32);
      na1 = loadA(1, s0 + 32);
    }
    #pragma unroll
    for (int mt = 0; mt < 4; ++mt)
      #pragma unroll
      for (int nt = 0; nt < 4; ++nt)
        acc[mt][nt] = __builtin_amdgcn_mfma_f32_16x16x32_bf16(fa[mt], fbr[nt], acc[mt][nt], 0, 0, 0);
    if (!more) break;
    // shift by 32 in distance: frag(mt) at s0+32 == frag(mt-2) at s0
    fa[3] = fa[1]; fa[2] = fa[0]; fa[1] = na1; fa[0] = na0;
    #pragma unroll
    for (int nt = 0; nt < 4; ++nt) fbr[nt] = nb[nt];
  }

  // Epilogue: double l2-norm over dd (softmax Z cancels up to eps terms ~3e-7).
  // C/D layout: col = lane&15 (dd offset), row = quad*4 + reg.
  #pragma unroll
  for (int mt = 0; mt < 4; ++mt) {
    #pragma unroll
    for (int r = 0; r < 4; ++r) {
      float ss = 0.0f;
      #pragma unroll
      for (int nt = 0; nt < 4; ++nt) { float a = acc[mt][nt][r]; ss += a * a; }
      ss += __shfl_xor(ss, 1);
      ss += __shfl_xor(ss, 2);
      ss += __shfl_xor(ss, 4);
      ss += __shfl_xor(ss, 8);
      int t = t0 + 16 * mt + 4 * quad + r;
      if (t <= T_DIM) {
        float n1 = sqrtf(ss);
        float u  = n1 / (n1 + EPS);
        float inv = 1.0f / ((n1 + EPS) * (u + EPS));
        float* op = out + (((size_t)(h * B_DIM + b) * TP1 + t) << 6) + lm;
        #pragma unroll
        for (int nt = 0; nt < 4; ++nt) op[16 * nt] = acc[mt][nt][r] * inv;
      }
    }
  }
}

// Head H: single l2norm of xp. 4 rows per 256-thread block, one wave per row.
__global__ __launch_bounds__(256) void xhat_out(const float* __restrict__ x,
                                               float* __restrict__ out) {
  int row = blockIdx.x * 4 + (threadIdx.x >> 6);
  if (row >= B_DIM * TP1) return;
  int b = row / TP1, t = row - b * TP1;
  int dd = threadIdx.x & 63;
  float v = (t < T_DIM) ? x[((size_t)b * T_DIM + t) * D_DIM + dd] : 0.0f;
  float ss = v * v;
  ss += __shfl_xor(ss, 1);
  ss += __shfl_xor(ss, 2);
  ss += __shfl_xor(ss, 4);
  ss += __shfl_xor(ss, 8);
  ss += __shfl_xor(ss, 16);
  ss += __shfl_xor(ss, 32);
  float inv = 1.0f / (sqrtf(ss) + EPS);
  out[(((size_t)(H_DIM * B_DIM + b) * TP1 + t) << 6) + dd] = v * inv;
}

extern "C" void kernel_launch(void* const* d_in, const int* in_sizes, int n_in,
                              void* d_out, int out_size, void* d_ws, size_t ws_size,
                              hipStream_t stream) {
  const float* x = (const float*)d_in[0];   // [8, 2048, 64] fp32
  const float* W = (const float*)d_in[1];   // [2048, 8] fp32
  float* out = (float*)d_out;               // [9, 8, 2049, 64] fp32

  unsigned short* xT    = (unsigned short*)d_ws;                    // 8*64*2080*2 = 2,129,920 B
  unsigned short* fragA = (unsigned short*)((char*)d_ws + 2131968); // 8*134*64*8*2 = 1,097,728 B

  hipLaunchKernelGGL(build_fragA, dim3(H_DIM * NFRAG), dim3(64), 0, stream, W, fragA);
  hipLaunchKernelGGL(transpose_x, dim3(B_DIM * 33), dim3(256), 0, stream, x, xT);
  hipLaunchKernelGGL(toeplitz_mm, dim3(64 * 33), dim3(64), 0, stream, fragA, xT, out);
  hipLaunchKernelGGL(xhat_out, dim3((B_DIM * TP1 + 3) / 4), dim3(256), 0, stream, x, out);
}

// Round 3
// 119.043 us; speedup vs baseline: 1.1271x; 1.0598x over previous
//
#include <hip/hip_runtime.h>

#define EPS 1e-7f
#define T_DIM 2048
#define TP1   2049
#define H_DIM 8
#define B_DIM 8
#define SP    2080   // padded xT row length (bf16 elements), 16B-aligned rows
#define NFRAG 134    // A-fragment table entries per head: b0 = fb*16 - 32
#define FB_OFF 32
#define RSTRIDE 66   // LDS reduction row stride: 4*66 % 32 == 8 -> only 2-way (free)

typedef short v8s __attribute__((ext_vector_type(8)));
typedef float v4f __attribute__((ext_vector_type(4)));

static __device__ __forceinline__ unsigned short f2bf(float f) {
  union { float f; unsigned u; } v; v.f = f;
  unsigned r = v.u + 0x7fffu + ((v.u >> 16) & 1u);  // RTNE
  return (unsigned short)(r >> 16);
}

#define J1_BLOCKS 268    // fragA: 8*134 frags * 64 lanes / 256
#define J2_BLOCKS 264    // transpose: 8 * 33
#define J3_BLOCKS 4098   // xhat: 8*2049 rows / 4

// Fused prep: [J1] MFMA A-fragment table, [J2] x -> bf16 transpose, [J3] head-H output.
__global__ __launch_bounds__(256) void prep(const float* __restrict__ x,
                                            const float* __restrict__ W,
                                            unsigned short* __restrict__ fragA,
                                            unsigned short* __restrict__ xT,
                                            float* __restrict__ out) {
  __shared__ float tile[64][65];
  int bid = blockIdx.x;
  if (bid < J1_BLOCKS) {
    // fragA[((h*NFRAG+fb)*64+lane)*8]: A[m=lm][k=quad*8+j] = k_h[b0+lm-8q-j]
    int tid = bid * 256 + threadIdx.x;
    int blk = tid >> 6, lane = tid & 63;
    int h = blk / NFRAG, fb = blk - h * NFRAG;
    int b0 = fb * 16 - FB_OFF;
    int lm = lane & 15, quad = lane >> 4;
    v8s frag;
    #pragma unroll
    for (int j = 0; j < 8; ++j) {
      int d = b0 + lm - 8 * quad - j;
      float v = 0.0f;
      if (d >= 0 && d < T_DIM) v = __expf(W[d * H_DIM + h]);
      else if (d == T_DIM) v = 1.0f;
      frag[j] = (short)f2bf(v);
    }
    *(v8s*)(fragA + (size_t)tid * 8) = frag;
    return;
  }
  bid -= J1_BLOCKS;
  if (bid < J2_BLOCKS) {
    int b = bid / 33, st = bid % 33;
    int tid = threadIdx.x;
    if (st == 32) {  // zero pad s in [2048, 2080)
      #pragma unroll
      for (int i = 0; i < 8; ++i) {
        int idx = tid * 8 + i;
        int dd = idx >> 5, sl = idx & 31;
        xT[((size_t)b * 64 + dd) * SP + T_DIM + sl] = 0;
      }
      return;
    }
    int s0 = st * 64;
    int c = tid & 63, r4 = tid >> 6;
    #pragma unroll
    for (int i = 0; i < 16; ++i) {
      int sl = r4 * 16 + i;
      tile[sl][c] = x[((size_t)b * T_DIM + (s0 + sl)) * 64 + c];
    }
    __syncthreads();
    #pragma unroll
    for (int i = 0; i < 16; ++i) {
      int dd = r4 * 16 + i;
      xT[((size_t)b * 64 + dd) * SP + s0 + c] = f2bf(tile[c][dd]);
    }
    return;
  }
  bid -= J2_BLOCKS;
  {  // head H: single l2norm of xp
    int row = bid * 4 + (threadIdx.x >> 6);
    if (row >= B_DIM * TP1) return;
    int b = row / TP1, t = row - b * TP1;
    int dd = threadIdx.x & 63;
    float v = (t < T_DIM) ? x[((size_t)b * T_DIM + t) * 64 + dd] : 0.0f;
    float ss = v * v;
    ss += __shfl_xor(ss, 1);  ss += __shfl_xor(ss, 2);
    ss += __shfl_xor(ss, 4);  ss += __shfl_xor(ss, 8);
    ss += __shfl_xor(ss, 16); ss += __shfl_xor(ss, 32);
    float inv = 1.0f / (sqrtf(ss) + EPS);
    out[(((size_t)(H_DIM * B_DIM + b) * TP1 + t) << 6) + dd] = v * inv;
  }
}

// 4 waves per block; block owns a 64(t) x 64(dd) tile of one (h,b).
// Wave w handles K-steps s0 = 32w + 128k  -> per-wave step distance 128:
// no fragment reuse between steps => pure double-buffered regs, zero v_mov.
// Cross-wave reduction in LDS, epilogue (double l2norm) on wave 0.
__global__ __launch_bounds__(256) void toeplitz_mm(const unsigned short* __restrict__ fragA,
                                                   const unsigned short* __restrict__ xT,
                                                   float* __restrict__ out) {
  __shared__ float bufA[64 * RSTRIDE];
  __shared__ float bufB[64 * RSTRIDE];

  const int lane = threadIdx.x & 63;
  const int w    = threadIdx.x >> 6;
  const int lm   = lane & 15;
  const int quad = lane >> 4;

  const int bi  = blockIdx.x;
  const int tt  = 32 - (bi >> 6);          // longest tiles first
  const int rem = bi & 63;
  const int h = rem >> 3, b = rem & 7;
  const int t0 = tt * 64;

  const unsigned short* fA = fragA + ((size_t)h * NFRAG * 64 + lane) * 8;
  const unsigned short* xb = xT + ((size_t)b * 64 + lm) * SP + 8 * quad;

  const int s_end = min(t0 + 32, T_DIM);   // last s0 (inclusive)

  v4f acc[4][4] = {};  // rows t0+16*mt+4*quad+r, cols 16*nt+lm

  v8s a0[4], a1[4], b0[4], b1[4];

#define LOAD_A(dst, s0v) do {                                        \
    const v8s* _p = (const v8s*)(fA + (size_t)(((t0 - (s0v) + FB_OFF) >> 4)) * 512); \
    dst[0] = _p[0]; dst[1] = _p[64]; dst[2] = _p[128]; dst[3] = _p[192]; } while (0)
#define LOAD_B(dst, s0v) do {                                        \
    const unsigned short* _p = xb + (s0v);                           \
    dst[0] = *(const v8s*)(_p);                                      \
    dst[1] = *(const v8s*)(_p + 16 * SP);                            \
    dst[2] = *(const v8s*)(_p + 32 * SP);                            \
    dst[3] = *(const v8s*)(_p + 48 * SP); } while (0)
#define DO_MFMA(fa, fb) do {                                         \
    _Pragma("unroll")                                                \
    for (int mt = 0; mt < 4; ++mt)                                   \
      _Pragma("unroll")                                              \
      for (int nt = 0; nt < 4; ++nt)                                 \
        acc[mt][nt] = __builtin_amdgcn_mfma_f32_16x16x32_bf16(fa[mt], fb[nt], acc[mt][nt], 0, 0, 0); } while (0)

  int s0 = 32 * w;
  if (s0 <= s_end) {
    LOAD_A(a0, s0); LOAD_B(b0, s0);
    for (;;) {
      bool more = (s0 + 128 <= s_end);
      if (more) { LOAD_A(a1, s0 + 128); LOAD_B(b1, s0 + 128); }
      DO_MFMA(a0, b0);
      if (!more) break;
      s0 += 128;
      bool more2 = (s0 + 128 <= s_end);
      if (more2) { LOAD_A(a0, s0 + 128); LOAD_B(b0, s0 + 128); }
      DO_MFMA(a1, b1);
      if (!more2) break;
      s0 += 128;
    }
  }

#define ST_ACC(buf) do {                                             \
    _Pragma("unroll")                                                \
    for (int mt = 0; mt < 4; ++mt)                                   \
      _Pragma("unroll")                                              \
      for (int r = 0; r < 4; ++r) {                                  \
        int row = 16 * mt + 4 * quad + r;                            \
        _Pragma("unroll")                                            \
        for (int nt = 0; nt < 4; ++nt)                               \
          buf[row * RSTRIDE + 16 * nt + lm] = acc[mt][nt][r]; } } while (0)
#define ADD_ACC(buf) do {                                            \
    _Pragma("unroll")                                                \
    for (int mt = 0; mt < 4; ++mt)                                   \
      _Pragma("unroll")                                              \
      for (int r = 0; r < 4; ++r) {                                  \
        int row = 16 * mt + 4 * quad + r;                            \
        _Pragma("unroll")                                            \
        for (int nt = 0; nt < 4; ++nt)                               \
          acc[mt][nt][r] += buf[row * RSTRIDE + 16 * nt + lm]; } } while (0)

  if (w == 1) ST_ACC(bufA);
  if (w == 3) ST_ACC(bufB);
  __syncthreads();
  if (w == 0) ADD_ACC(bufA);
  if (w == 2) ADD_ACC(bufB);
  __syncthreads();
  if (w == 2) ST_ACC(bufA);
  __syncthreads();
  if (w != 0) return;
  ADD_ACC(bufA);

  // Epilogue: double l2-norm over dd (softmax Z cancels up to eps ~3e-7).
  #pragma unroll
  for (int mt = 0; mt < 4; ++mt) {
    #pragma unroll
    for (int r = 0; r < 4; ++r) {
      float ss = 0.0f;
      #pragma unroll
      for (int nt = 0; nt < 4; ++nt) { float a = acc[mt][nt][r]; ss += a * a; }
      ss += __shfl_xor(ss, 1);
      ss += __shfl_xor(ss, 2);
      ss += __shfl_xor(ss, 4);
      ss += __shfl_xor(ss, 8);
      int t = t0 + 16 * mt + 4 * quad + r;
      if (t <= T_DIM) {
        float n1 = sqrtf(ss);
        float u  = n1 / (n1 + EPS);
        float inv = 1.0f / ((n1 + EPS) * (u + EPS));
        float* op = out + (((size_t)(h * B_DIM + b) * TP1 + t) << 6) + lm;
        #pragma unroll
        for (int nt = 0; nt < 4; ++nt) op[16 * nt] = acc[mt][nt][r] * inv;
      }
    }
  }
}

extern "C" void kernel_launch(void* const* d_in, const int* in_sizes, int n_in,
                              void* d_out, int out_size, void* d_ws, size_t ws_size,
                              hipStream_t stream) {
  const float* x = (const float*)d_in[0];   // [8, 2048, 64] fp32
  const float* W = (const float*)d_in[1];   // [2048, 8] fp32
  float* out = (float*)d_out;               // [9, 8, 2049, 64] fp32

  unsigned short* xT    = (unsigned short*)d_ws;                    // 8*64*2080*2 = 2,129,920 B
  unsigned short* fragA = (unsigned short*)((char*)d_ws + 2131968); // 8*134*64*8*2 = 1,097,728 B

  hipLaunchKernelGGL(prep, dim3(J1_BLOCKS + J2_BLOCKS + J3_BLOCKS), dim3(256), 0, stream,
                     x, W, fragA, xT, out);
  hipLaunchKernelGGL(toeplitz_mm, dim3(64 * 33), dim3(256), 0, stream, fragA, xT, out);
}

// Round 4
// 115.142 us; speedup vs baseline: 1.1653x; 1.0339x over previous
//
#include <hip/hip_runtime.h>

#define EPS 1e-7f
#define T_DIM 2048
#define TP1   2049
#define H_DIM 8
#define B_DIM 8
#define SP    2080   // padded xT row length (bf16 elements), 16B-aligned rows
#define NFRAG 138    // A-fragment table entries per head: b0 = fb*16 - 32, fb in [0,138)
#define FB_OFF 32
#define RSTRIDE 66   // LDS reduction row stride

typedef short v8s __attribute__((ext_vector_type(8)));
typedef float v4f __attribute__((ext_vector_type(4)));

static __device__ __forceinline__ unsigned short f2bf(float f) {
  union { float f; unsigned u; } v; v.f = f;
  unsigned r = v.u + 0x7fffu + ((v.u >> 16) & 1u);  // RTNE
  return (unsigned short)(r >> 16);
}

#define J1_BLOCKS 276    // fragA: 8*138 frags * 64 lanes / 256
#define J2_BLOCKS 264    // transpose: 8 * 33
#define J3_BLOCKS 4098   // xhat: 8*2049 rows / 4

// Fused prep: [J1] MFMA A-fragment table, [J2] x -> bf16 transpose, [J3] head-H output.
__global__ __launch_bounds__(256) void prep(const float* __restrict__ x,
                                            const float* __restrict__ W,
                                            unsigned short* __restrict__ fragA,
                                            unsigned short* __restrict__ xT,
                                            float* __restrict__ out) {
  __shared__ float tile[64][65];
  int bid = blockIdx.x;
  if (bid < J1_BLOCKS) {
    // fragA[((h*NFRAG+fb)*64+lane)*8]: A[m=lm][k=quad*8+j] = k_h[b0+lm-8q-j], b0=fb*16-32
    int tid = bid * 256 + threadIdx.x;
    int blk = tid >> 6, lane = tid & 63;
    int h = blk / NFRAG, fb = blk - h * NFRAG;
    int b0 = fb * 16 - FB_OFF;
    int lm = lane & 15, quad = lane >> 4;
    v8s frag;
    #pragma unroll
    for (int j = 0; j < 8; ++j) {
      int d = b0 + lm - 8 * quad - j;
      float v = 0.0f;
      if (d >= 0 && d < T_DIM) v = __expf(W[d * H_DIM + h]);
      else if (d == T_DIM) v = 1.0f;
      frag[j] = (short)f2bf(v);
    }
    *(v8s*)(fragA + (size_t)tid * 8) = frag;
    return;
  }
  bid -= J1_BLOCKS;
  if (bid < J2_BLOCKS) {
    int b = bid / 33, st = bid % 33;
    int tid = threadIdx.x;
    if (st == 32) {  // zero pad s in [2048, 2080)
      #pragma unroll
      for (int i = 0; i < 8; ++i) {
        int idx = tid * 8 + i;
        int dd = idx >> 5, sl = idx & 31;
        xT[((size_t)b * 64 + dd) * SP + T_DIM + sl] = 0;
      }
      return;
    }
    int s0 = st * 64;
    int c = tid & 63, r4 = tid >> 6;
    #pragma unroll
    for (int i = 0; i < 16; ++i) {
      int sl = r4 * 16 + i;
      tile[sl][c] = x[((size_t)b * T_DIM + (s0 + sl)) * 64 + c];
    }
    __syncthreads();
    #pragma unroll
    for (int i = 0; i < 16; ++i) {
      int dd = r4 * 16 + i;
      xT[((size_t)b * 64 + dd) * SP + s0 + c] = f2bf(tile[c][dd]);
    }
    return;
  }
  bid -= J2_BLOCKS;
  {  // head H: single l2norm of xp
    int row = bid * 4 + (threadIdx.x >> 6);
    if (row >= B_DIM * TP1) return;
    int b = row / TP1, t = row - b * TP1;
    int dd = threadIdx.x & 63;
    float v = (t < T_DIM) ? x[((size_t)b * T_DIM + t) * 64 + dd] : 0.0f;
    float ss = v * v;
    ss += __shfl_xor(ss, 1);  ss += __shfl_xor(ss, 2);
    ss += __shfl_xor(ss, 4);  ss += __shfl_xor(ss, 8);
    ss += __shfl_xor(ss, 16); ss += __shfl_xor(ss, 32);
    float inv = 1.0f / (sqrtf(ss) + EPS);
    __builtin_nontemporal_store(v * inv,
        &out[(((size_t)(H_DIM * B_DIM + b) * TP1 + t) << 6) + dd]);
  }
}

// Block = 128(t) x 64(dd) tile of one (h,b); 4 waves: wm = w&1 owns a 64-row half,
// wk = w>>1 splits K (s0 = 32*wk + 64*k). Same-wk waves share B lines (L1 temporal),
// same-wm waves cover interleaved A-fragment ranges (L1 temporal). Per-wave causal
// cap: sw_end = min(t0 + 64*wm + 32, 2048). Output stores are non-temporal so the
// streaming writes don't evict fragA/xT from L2. h = bi&7 pins one head per XCD
// (round-robin dispatch) -> per-XCD L2 working set ~2.3 MB.
__global__ __launch_bounds__(256) void toeplitz_mm(const unsigned short* __restrict__ fragA,
                                                   const unsigned short* __restrict__ xT,
                                                   float* __restrict__ out) {
  __shared__ float red[2][64 * RSTRIDE];

  const int lane = threadIdx.x & 63;
  const int w    = threadIdx.x >> 6;
  const int wm   = w & 1;
  const int wk   = w >> 1;
  const int lm   = lane & 15;
  const int quad = lane >> 4;

  const int bi  = blockIdx.x;
  const int tb  = 16 - (bi >> 6);          // longest tiles first
  const int rem = bi & 63;
  const int h = rem & 7, b = (rem >> 3) & 7;
  const int t0 = tb * 128;
  const int tw = t0 + 64 * wm;             // this wave's row base

  const unsigned short* fA = fragA + ((size_t)h * NFRAG * 64 + lane) * 8;
  const unsigned short* xb = xT + ((size_t)b * 64 + lm) * SP + 8 * quad;

  const int sw_end = min(tw + 32, T_DIM);  // last s0 (inclusive) for this wave

  v4f acc[4][4] = {};  // rows tw+16*mt+4*quad+r, cols 16*nt+lm

  v8s a0[4], a1[4], b0[4], b1[4];

#define LOAD_A(dst, s0v) do {                                        \
    const v8s* _p = (const v8s*)(fA + (size_t)((tw - (s0v) + FB_OFF) >> 4) * 512); \
    dst[0] = _p[0]; dst[1] = _p[64]; dst[2] = _p[128]; dst[3] = _p[192]; } while (0)
#define LOAD_B(dst, s0v) do {                                        \
    const unsigned short* _p = xb + (s0v);                           \
    dst[0] = *(const v8s*)(_p);                                      \
    dst[1] = *(const v8s*)(_p + 16 * SP);                            \
    dst[2] = *(const v8s*)(_p + 32 * SP);                            \
    dst[3] = *(const v8s*)(_p + 48 * SP); } while (0)
#define DO_MFMA(fa, fb) do {                                         \
    _Pragma("unroll")                                                \
    for (int mt = 0; mt < 4; ++mt)                                   \
      _Pragma("unroll")                                              \
      for (int nt = 0; nt < 4; ++nt)                                 \
        acc[mt][nt] = __builtin_amdgcn_mfma_f32_16x16x32_bf16(fa[mt], fb[nt], acc[mt][nt], 0, 0, 0); } while (0)

  int s0 = 32 * wk;
  LOAD_A(a0, s0); LOAD_B(b0, s0);
  for (;;) {
    bool more = (s0 + 64 <= sw_end);
    if (more) { LOAD_A(a1, s0 + 64); LOAD_B(b1, s0 + 64); }
    DO_MFMA(a0, b0);
    if (!more) break;
    s0 += 64;
    bool more2 = (s0 + 64 <= sw_end);
    if (more2) { LOAD_A(a0, s0 + 64); LOAD_B(b0, s0 + 64); }
    DO_MFMA(a1, b1);
    if (!more2) break;
    s0 += 64;
  }

  // wk=1 waves dump partial sums; wk=0 waves reduce + epilogue. One barrier.
  if (wk == 1) {
    float* buf = red[wm];
    #pragma unroll
    for (int mt = 0; mt < 4; ++mt)
      #pragma unroll
      for (int r = 0; r < 4; ++r) {
        int row = 16 * mt + 4 * quad + r;
        #pragma unroll
        for (int nt = 0; nt < 4; ++nt)
          buf[row * RSTRIDE + 16 * nt + lm] = acc[mt][nt][r];
      }
  }
  __syncthreads();
  if (wk != 0) return;

  const float* buf = red[wm];
  #pragma unroll
  for (int mt = 0; mt < 4; ++mt) {
    #pragma unroll
    for (int r = 0; r < 4; ++r) {
      int row = 16 * mt + 4 * quad + r;
      #pragma unroll
      for (int nt = 0; nt < 4; ++nt)
        acc[mt][nt][r] += buf[row * RSTRIDE + 16 * nt + lm];
    }
  }

  // Epilogue: double l2-norm over dd (softmax Z cancels up to eps ~3e-7).
  // C/D layout: col = lane&15 (dd offset), row = quad*4 + reg.
  #pragma unroll
  for (int mt = 0; mt < 4; ++mt) {
    #pragma unroll
    for (int r = 0; r < 4; ++r) {
      float ss = 0.0f;
      #pragma unroll
      for (int nt = 0; nt < 4; ++nt) { float a = acc[mt][nt][r]; ss += a * a; }
      ss += __shfl_xor(ss, 1);
      ss += __shfl_xor(ss, 2);
      ss += __shfl_xor(ss, 4);
      ss += __shfl_xor(ss, 8);
      int t = tw + 16 * mt + 4 * quad + r;
      if (t <= T_DIM) {
        float n1 = sqrtf(ss);
        float u  = n1 / (n1 + EPS);
        float inv = 1.0f / ((n1 + EPS) * (u + EPS));
        float* op = out + (((size_t)(h * B_DIM + b) * TP1 + t) << 6) + lm;
        #pragma unroll
        for (int nt = 0; nt < 4; ++nt)
          __builtin_nontemporal_store(acc[mt][nt][r] * inv, op + 16 * nt);
      }
    }
  }
}

extern "C" void kernel_launch(void* const* d_in, const int* in_sizes, int n_in,
                              void* d_out, int out_size, void* d_ws, size_t ws_size,
                              hipStream_t stream) {
  const float* x = (const float*)d_in[0];   // [8, 2048, 64] fp32
  const float* W = (const float*)d_in[1];   // [2048, 8] fp32
  float* out = (float*)d_out;               // [9, 8, 2049, 64] fp32

  unsigned short* xT    = (unsigned short*)d_ws;                    // 8*64*2080*2 = 2,129,920 B
  unsigned short* fragA = (unsigned short*)((char*)d_ws + 2131968); // 8*138*64*8*2 = 1,130,496 B

  hipLaunchKernelGGL(prep, dim3(J1_BLOCKS + J2_BLOCKS + J3_BLOCKS), dim3(256), 0, stream,
                     x, W, fragA, xT, out);
  hipLaunchKernelGGL(toeplitz_mm, dim3(64 * 17), dim3(256), 0, stream, fragA, xT, out);
}